// Round 1
// 587.531 us; speedup vs baseline: 1.2459x; 1.2459x over previous
//
#include <hip/hip_runtime.h>
#include <hip/hip_bf16.h>
#include <math.h>
#include <stdint.h>

typedef __bf16 bf16;
typedef __bf16 bf16x8 __attribute__((ext_vector_type(8)));
typedef float  floatx4 __attribute__((ext_vector_type(4)));

#define HEADS 8
#define DH    64
#define NB    8
#define NTOK  4096
#define CDIM  512
#define MTOT  32768
#define PART_STRIDE 16777216L   // elements: 32768*512

// async global->LDS, 16B per lane; LDS dst = wave-uniform base + lane*16 (m97/m104)
__device__ __forceinline__ void gload16(const bf16* g, bf16* l) {
    __builtin_amdgcn_global_load_lds(
        (const __attribute__((address_space(1))) unsigned int*)g,
        (__attribute__((address_space(3))) unsigned int*)l,
        16, 0, 0);
}

__global__ void detect_kernel(const bf16* __restrict__ w, int* __restrict__ flag)
{
    __shared__ int cnt[256];
    int c = 0;
    for (int i = 0; i < 64; ++i) {
        float v = fabsf((float)w[threadIdx.x + i * 256]);
        if (v > 1e3f) c++;
    }
    cnt[threadIdx.x] = c;
    __syncthreads();
    if (threadIdx.x == 0) {
        int s = 0;
        for (int i = 0; i < 256; ++i) s += cnt[i];
        *flag = (s > 500) ? 1 : 0;   // 1 => inputs are fp32
    }
}

// misc floats: [0..7] temp0, [8..15] temp1, [16..527] bias0, [528..1039] bias1
__global__ void misc_kernel(const void* t0, const void* t1, const void* b0, const void* b1,
                            const int* __restrict__ flag, float* __restrict__ misc)
{
    bool f32 = (*flag != 0);
    int tid = threadIdx.x;
    #define RD(p, i) (f32 ? ((const float*)(p))[i] : (float)((const bf16*)(p))[i])
    if (tid < 8) { misc[tid] = RD(t0, tid); misc[8 + tid] = RD(t1, tid); }
    for (int i = tid; i < 512; i += 256) {
        misc[16 + i]  = RD(b0, i);
        misc[528 + i] = RD(b1, i);
    }
    #undef RD
}

__global__ void wt_kernel(const void* __restrict__ W, bf16* __restrict__ Wt, int K, int N,
                          const int* __restrict__ flag)
{
    int idx = blockIdx.x * 256 + threadIdx.x;
    if (idx >= K * N) return;
    bool f32 = (*flag != 0);
    int n = idx / K;
    int k = idx - n * K;
    float v = f32 ? ((const float*)W)[k * N + n] : (float)((const bf16*)W)[k * N + n];
    Wt[idx] = (bf16)v;
}

// X (fp32 or bf16 per flag) -> Y bf16; 8 elements/thread, 16,777,216 elements
__global__ void cast_kernel(const void* __restrict__ X, bf16* __restrict__ Y,
                            const int* __restrict__ flag)
{
    size_t i = ((size_t)blockIdx.x * 256 + threadIdx.x) * 8;
    if (*flag) {
        const float* xf = (const float*)X + i;
        float4 a = *(const float4*)xf;
        float4 b = *(const float4*)(xf + 4);
        bf16 t[8] = {(bf16)a.x, (bf16)a.y, (bf16)a.z, (bf16)a.w,
                     (bf16)b.x, (bf16)b.y, (bf16)b.z, (bf16)b.w};
        *(uint4*)(Y + i) = *(uint4*)t;
    } else {
        *(uint4*)(Y + i) = *(const uint4*)((const bf16*)X + i);
    }
}

// ---------------------------------------------------------------------------
// C = A[M][512] * Bt[N][512]^T (+bias), bf16 in, K=512 fixed.
// 256x256 tile, BK=64, 512 thr / 8 waves (2M x 4N), per-wave 128x64 output.
// 8-phase pipelined schedule (m201 template): per K-tile, 4 quadrant phases
// {ds_read subtile | issue half-tile gload_lds | barrier | 16 MFMA | barrier},
// counted vmcnt(4) once per tile (never 0 in steady state).
// LDS: 2 bufs x (A,B) x 2 half-tiles(128x64) = 128 KiB, double-buffered.
// Bank swizzle: 16B-slot ^= (row&7), applied as inverse-swizzled GLOBAL source
// (linear gload_lds dest) + swizzled ds_read (rule #21).
// Region lifetimes (quadrants q0..q3 = (Mlo,Nlo),(Mlo,Nhi),(Mhi,Nhi),(Mhi,Nlo)):
//   B halves last read in q1, A halves in q2. Issue schedule:
//   q0: B1(t+1), q1: A1(t+1), q2: B0(t+2), q3: A0(t+2)  -> all dest-dead. At
//   q3 end, tile t+1 fully landed with <=4 loads (B0/A0 of t+2) outstanding.
// ---------------------------------------------------------------------------
__global__ __launch_bounds__(512, 2) void gemm_bt(
    const bf16* __restrict__ A, const bf16* __restrict__ Bt,
    const float* __restrict__ bias, void* __restrict__ C, bf16* __restrict__ Cv,
    long c_base, const int* __restrict__ cflag)
{
    __shared__ bf16 lds[2][2][2][128 * 64];   // [buf][A=0/B=1][half][row*64 + swz-slot]

    const int tid  = threadIdx.x;
    const int lane = tid & 63;
    const int w    = tid >> 6;
    const int wmi  = w >> 2;        // 0..1 : wave M-half
    const int wni  = w & 3;         // 0..3 : wave N-quarter
    const int l15  = lane & 15;
    const int quad = lane >> 4;

    const int m0 = blockIdx.x * 256;
    const int n0 = blockIdx.y * 256;

    // staging: inst i in {0,1}: local row = w*16 + i*8 + (lane>>3), phys slot p = lane&7,
    // fetch logical 16B slot s = p ^ (row&7)  (row&7 invariant under +8)
    const int rl0 = w * 16 + (lane >> 3);
    const int swz = ((lane & 7) ^ (rl0 & 7)) * 8;      // element offset of fetched chunk
    const bf16* Abase = A  + (size_t)(m0 + rl0) * 512 + swz;
    const bf16* Bbase = Bt + (size_t)(n0 + rl0) * 512 + swz;
    const int ldst0 = w * 1024;                         // LDS element offset, inst0

    // compute side: logical slot s = ks*4+quad, phys slot = s ^ (row&7), row&7 == l15&7
    const int rxor  = l15 & 7;
    const int k0off = (quad ^ rxor) * 8;
    const int k1off = ((4 + quad) ^ rxor) * 8;
    const bf16* Ah0 = &lds[0][0][wmi][l15 * 64];
    const bf16* Ah1 = &lds[1][0][wmi][l15 * 64];
    const bf16* Bh0 = &lds[0][1][wni >> 1][((wni & 1) * 64 + l15) * 64];
    const bf16* Bh1 = &lds[1][1][wni >> 1][((wni & 1) * 64 + l15) * 64];

    bf16x8 aR[4][2], bR[4][2];
    floatx4 acc[8][4] = {};

#define STAGE_A(b, h, t) do { \
    const bf16* _g = Abase + (h) * 65536 + (t) * 64; \
    gload16(_g,        &lds[b][0][h][ldst0]); \
    gload16(_g + 4096, &lds[b][0][h][ldst0 + 512]); \
} while (0)
#define STAGE_B(b, h, t) do { \
    const bf16* _g = Bbase + (h) * 65536 + (t) * 64; \
    gload16(_g,        &lds[b][1][h][ldst0]); \
    gload16(_g + 4096, &lds[b][1][h][ldst0 + 512]); \
} while (0)
#define RD_A(b, qm) do { \
    _Pragma("unroll") for (int _i = 0; _i < 4; ++_i) { \
        aR[_i][0] = *(const bf16x8*)(Ah##b + ((qm) * 4 + _i) * 1024 + k0off); \
        aR[_i][1] = *(const bf16x8*)(Ah##b + ((qm) * 4 + _i) * 1024 + k1off); \
    } \
} while (0)
#define RD_B(b, qn) do { \
    _Pragma("unroll") for (int _j = 0; _j < 2; ++_j) { \
        bR[(qn) * 2 + _j][0] = *(const bf16x8*)(Bh##b + ((qn) * 2 + _j) * 1024 + k0off); \
        bR[(qn) * 2 + _j][1] = *(const bf16x8*)(Bh##b + ((qn) * 2 + _j) * 1024 + k1off); \
    } \
} while (0)
#define MM(qm, qn) do { \
    _Pragma("unroll") for (int _i = 0; _i < 4; ++_i) \
    _Pragma("unroll") for (int _j = 0; _j < 2; ++_j) { \
        acc[(qm)*4+_i][(qn)*2+_j] = __builtin_amdgcn_mfma_f32_16x16x32_bf16( \
            aR[_i][0], bR[(qn)*2+_j][0], acc[(qm)*4+_i][(qn)*2+_j], 0, 0, 0); \
        acc[(qm)*4+_i][(qn)*2+_j] = __builtin_amdgcn_mfma_f32_16x16x32_bf16( \
            aR[_i][1], bR[(qn)*2+_j][1], acc[(qm)*4+_i][(qn)*2+_j], 0, 0, 0); \
    } \
} while (0)
#define SYNC   asm volatile("s_barrier" ::: "memory")
#define VMW(n) asm volatile("s_waitcnt vmcnt(" #n ")" ::: "memory")
#define PRIO1  __builtin_amdgcn_s_setprio(1)
#define PRIO0  __builtin_amdgcn_s_setprio(0)

#define TILE(t, b, nb, W) do { \
    /* q0 (Mlo,Nlo) */ \
    RD_A(b, 0); RD_B(b, 0); \
    if ((t) + 1 < 8) STAGE_B(nb, 1, (t) + 1); \
    SYNC; PRIO1; MM(0, 0); PRIO0; SYNC; \
    /* q1 (Mlo,Nhi) */ \
    RD_B(b, 1); \
    if ((t) + 1 < 8) STAGE_A(nb, 1, (t) + 1); \
    SYNC; PRIO1; MM(0, 1); PRIO0; SYNC; \
    /* q2 (Mhi,Nhi) */ \
    RD_A(b, 1); \
    if ((t) + 2 < 8) STAGE_B(b, 0, (t) + 2); \
    SYNC; PRIO1; MM(1, 1); PRIO0; SYNC; \
    /* q3 (Mhi,Nlo) */ \
    if ((t) + 2 < 8) STAGE_A(b, 0, (t) + 2); \
    SYNC; PRIO1; MM(1, 0); PRIO0; \
    VMW(W); SYNC; \
} while (0)

    // prologue: tile0 (4 halves) + B0/A0 of tile1; then tile0 done with 4 in flight
    STAGE_A(0, 0, 0); STAGE_A(0, 1, 0); STAGE_B(0, 0, 0); STAGE_B(0, 1, 0);
    STAGE_B(1, 0, 1); STAGE_A(1, 0, 1);
    VMW(4);
    SYNC;

    TILE(0, 0, 1, 4);
    TILE(1, 1, 0, 4);
    TILE(2, 0, 1, 4);
    TILE(3, 1, 0, 4);
    TILE(4, 0, 1, 4);
    TILE(5, 1, 0, 4);
    TILE(6, 0, 1, 0);   // tail: prefetches of t+2 skipped -> drain before tile 7
    TILE(7, 1, 0, 0);

#undef TILE
#undef STAGE_A
#undef STAGE_B
#undef RD_A
#undef RD_B
#undef MM
#undef SYNC
#undef VMW
#undef PRIO1
#undef PRIO0

    // epilogue: D layout col=lane&15, row=quad*4+reg (m89/m91).
    // n-range of a block (256 wide, n0 multiple of 256) sits in a single part.
    const bool cf32 = cflag && (*cflag != 0);
    const int  part = n0 >> 9;
    const long rowB = (long)m0 + wmi * 128 + quad * 4;
    const int  colB = (n0 & 511) + wni * 64 + l15;

    float bv[4];
    #pragma unroll
    for (int fj = 0; fj < 4; ++fj)
        bv[fj] = bias ? bias[n0 + wni * 64 + fj * 16 + l15] : 0.0f;

    if (part == 2) {
        #pragma unroll
        for (int fi = 0; fi < 8; ++fi)
            #pragma unroll
            for (int rr = 0; rr < 4; ++rr) {
                bf16* op = Cv + (rowB + fi * 16 + rr) * CDIM + colB;
                #pragma unroll
                for (int fj = 0; fj < 4; ++fj)
                    op[fj * 16] = (bf16)acc[fi][fj][rr];
            }
    } else if (cf32) {
        float* Cp = (float*)C + c_base + (long)part * PART_STRIDE;
        #pragma unroll
        for (int fi = 0; fi < 8; ++fi)
            #pragma unroll
            for (int rr = 0; rr < 4; ++rr) {
                float* op = Cp + (rowB + fi * 16 + rr) * CDIM + colB;
                #pragma unroll
                for (int fj = 0; fj < 4; ++fj)
                    op[fj * 16] = acc[fi][fj][rr] + bv[fj];
            }
    } else {
        bf16* Cp = (bf16*)C + c_base + (long)part * PART_STRIDE;
        #pragma unroll
        for (int fi = 0; fi < 8; ++fi)
            #pragma unroll
            for (int rr = 0; rr < 4; ++rr) {
                bf16* op = Cp + (rowB + fi * 16 + rr) * CDIM + colB;
                #pragma unroll
                for (int fj = 0; fj < 4; ++fj)
                    op[fj * 16] = (bf16)(acc[fi][fj][rr] + bv[fj]);
            }
    }
}

__device__ inline void unpack8(uint4 u, float* dst) {
    uint32_t w[4] = {u.x, u.y, u.z, u.w};
    #pragma unroll
    for (int i = 0; i < 4; ++i) {
        dst[2 * i]     = __uint_as_float(w[i] << 16);
        dst[2 * i + 1] = __uint_as_float(w[i] & 0xffff0000u);
    }
}

__global__ __launch_bounds__(256) void xca_gk(
    const bf16* __restrict__ Q0, const bf16* __restrict__ K0,
    const bf16* __restrict__ Q1, const bf16* __restrict__ K1,
    float* __restrict__ G, float* __restrict__ NQ, float* __restrict__ NK)
{
    __shared__ float qc[64][68];
    __shared__ float kc[64][68];

    int bid = blockIdx.x;
    int nq4 = bid & 3;
    int h   = (bid >> 2) & 7;
    int b   = (bid >> 5) & 7;
    int s   = bid >> 8;
    int sbh = s * 64 + b * 8 + h;

    const bf16* qsrc = s ? Q1 : Q0;
    const bf16* ksrc = s ? K0 : K1;

    int tid  = threadIdx.x;
    int nloc = tid >> 2;
    int d8   = (tid & 3) * 8;
    int d0   = (tid >> 4) * 4;
    int e0   = (tid & 15) * 4;

    float acc[4][4] = {};
    float nacc = 0.f;

    int n_start = nq4 * 1024;
    for (int ch = 0; ch < 16; ++ch) {
        int ng = n_start + ch * 64 + nloc;
        const bf16* qp = qsrc + (long)(b * NTOK + ng) * CDIM + h * DH;
        const bf16* kp = ksrc + (long)(b * NTOK + ng) * CDIM + h * DH;
        uint4 qA = *(const uint4*)(qp + d8);
        uint4 qB = *(const uint4*)(qp + 32 + d8);
        uint4 kA = *(const uint4*)(kp + d8);
        uint4 kB = *(const uint4*)(kp + 32 + d8);
        __syncthreads();
        unpack8(qA, &qc[nloc][d8]);
        unpack8(qB, &qc[nloc][32 + d8]);
        unpack8(kA, &kc[nloc][d8]);
        unpack8(kB, &kc[nloc][32 + d8]);
        __syncthreads();

        if (tid < 64) {
            #pragma unroll 8
            for (int n = 0; n < 64; ++n) { float v = qc[n][tid]; nacc += v * v; }
        } else if (tid < 128) {
            int dd = tid - 64;
            #pragma unroll 8
            for (int n = 0; n < 64; ++n) { float v = kc[n][dd]; nacc += v * v; }
        }
        #pragma unroll 4
        for (int n = 0; n < 64; ++n) {
            floatx4 qd = *(floatx4*)&qc[n][d0];
            floatx4 ke = *(floatx4*)&kc[n][e0];
            #pragma unroll
            for (int i = 0; i < 4; ++i)
                #pragma unroll
                for (int j = 0; j < 4; ++j)
                    acc[i][j] += qd[i] * ke[j];
        }
    }
    float* Gp = G + (sbh * 64 + d0) * 64 + e0;
    #pragma unroll
    for (int i = 0; i < 4; ++i)
        #pragma unroll
        for (int j = 0; j < 4; ++j)
            atomicAdd(&Gp[i * 64 + j], acc[i][j]);
    if (tid < 64)       atomicAdd(&NQ[sbh * 64 + tid], nacc);
    else if (tid < 128) atomicAdd(&NK[sbh * 64 + tid - 64], nacc);
}

__global__ void xca_soft(const float* __restrict__ G,
                         const float* __restrict__ NQ, const float* __restrict__ NK,
                         const float* __restrict__ misc, bf16* __restrict__ P)
{
    int sbh = blockIdx.x;
    int s = sbh >> 6;
    int h = sbh & 7;
    int d = threadIdx.x;

    __shared__ float rk[64];
    rk[d] = 1.0f / fmaxf(sqrtf(NK[sbh * 64 + d]), 1e-12f);
    __syncthreads();

    float rq = 1.0f / fmaxf(sqrtf(NQ[sbh * 64 + d]), 1e-12f);
    float t  = misc[s * 8 + h];
    const float* Gr = G + (sbh * 64 + d) * 64;

    float a[64];
    float mx = -1e30f;
    #pragma unroll
    for (int e = 0; e < 64; ++e) {
        a[e] = Gr[e] * rq * rk[e] * t;
        mx = fmaxf(mx, a[e]);
    }
    float sum = 0.f;
    #pragma unroll
    for (int e = 0; e < 64; ++e) { a[e] = expf(a[e] - mx); sum += a[e]; }
    float inv = 1.0f / sum;
    bf16* Pr = P + (sbh * 64 + d) * 64;
    #pragma unroll
    for (int e = 0; e < 64; ++e) Pr[e] = (bf16)(a[e] * inv);
}

__global__ __launch_bounds__(256) void xca_pv(
    const bf16* __restrict__ V0, const bf16* __restrict__ V1,
    const bf16* __restrict__ P, bf16* __restrict__ xca)
{
    int bid = blockIdx.x;
    int nq4 = bid & 3;
    int h   = (bid >> 2) & 7;
    int b   = (bid >> 5) & 7;
    int s   = bid >> 8;
    int sbh = s * 64 + b * 8 + h;

    const bf16* vsrc = s ? V0 : V1;

    int tid = threadIdx.x;
    int lane = tid & 63;
    int wave = tid >> 6;
    int l15 = lane & 15;
    int quad = lane >> 4;

    const bf16* Pb = P + sbh * 4096;
    bf16x8 pf[4][2];
    #pragma unroll
    for (int i = 0; i < 4; ++i)
        #pragma unroll
        for (int h2 = 0; h2 < 2; ++h2)
            pf[i][h2] = *(const bf16x8*)&Pb[(i * 16 + l15) * 64 + h2 * 32 + quad * 8];

    int n_start = nq4 * 1024 + wave * 256;
    for (int nt = 0; nt < 16; ++nt) {
        int nb = n_start + nt * 16;
        const bf16* vp = vsrc + (long)(b * NTOK + nb + l15) * CDIM + h * DH + quad * 8;
        bf16x8 v0 = *(const bf16x8*)vp;
        bf16x8 v1 = *(const bf16x8*)(vp + 32);
        floatx4 acc[4] = {};
        #pragma unroll
        for (int i = 0; i < 4; ++i) {
            acc[i] = __builtin_amdgcn_mfma_f32_16x16x32_bf16(v0, pf[i][0], acc[i], 0, 0, 0);
            acc[i] = __builtin_amdgcn_mfma_f32_16x16x32_bf16(v1, pf[i][1], acc[i], 0, 0, 0);
        }
        bf16* op = xca + (long)((s * NB + b) * NTOK + nb + quad * 4) * CDIM + h * DH + l15;
        #pragma unroll
        for (int i = 0; i < 4; ++i)
            #pragma unroll
            for (int r = 0; r < 4; ++r)
                op[(long)r * CDIM + i * 16] = (bf16)acc[i][r];
    }
}

// ws layout (bytes), total ~208.7 MB:
//   0           Q0 (33,554,432)
//   33,554,432  K0 (33,554,432)
//   67,108,864  Q1 (33,554,432)
//   100,663,296 K1 (33,554,432)
//   134,217,728 Xb0 (33,554,432)  -- bf16 cast of x;  xca overlay after QKV gemms
//   167,772,160 Xb1 (33,554,432)  -- bf16 cast of x_d
//   201,326,592 wtq0 (1,572,864)
//   202,899,456 wtq1 (1,572,864)
//   204,472,320 wtp0 (524,288)
//   204,996,608 wtp1 (524,288)
//   205,520,896 G    (2,097,152 fp32)
//   207,618,048 NQ   (32,768)
//   207,650,816 NK   (32,768)
//   207,683,584 P    (1,048,576)
//   208,732,160 flag (64)
//   208,732,224 misc (4,160)
// V0/V1 in d_out (dead scratch until the final proj overwrites it).
extern "C" void kernel_launch(void* const* d_in, const int* in_sizes, int n_in,
                              void* d_out, int out_size, void* d_ws, size_t ws_size,
                              hipStream_t stream)
{
    const void* x     = d_in[0];
    const void* x_d   = d_in[1];
    const void* Wq0   = d_in[2];
    const void* Wq1   = d_in[3];
    const void* temp0 = d_in[4];
    const void* temp1 = d_in[5];
    const void* Wp0   = d_in[6];
    const void* bp0   = d_in[7];
    const void* Wp1   = d_in[8];
    const void* bp1   = d_in[9];

    char* ws = (char*)d_ws;
    bf16*  Q0   = (bf16*)(ws);
    bf16*  K0   = (bf16*)(ws + 33554432);
    bf16*  Q1   = (bf16*)(ws + 67108864);
    bf16*  K1   = (bf16*)(ws + 100663296);
    bf16*  Xb0  = (bf16*)(ws + 134217728);
    bf16*  Xb1  = (bf16*)(ws + 167772160);
    bf16*  xca  = (bf16*)(ws + 134217728);  // overlay on Xb0+Xb1 (dead after QKV gemms)
    bf16*  wtq0 = (bf16*)(ws + 201326592);
    bf16*  wtq1 = (bf16*)(ws + 202899456);
    bf16*  wtp0 = (bf16*)(ws + 204472320);
    bf16*  wtp1 = (bf16*)(ws + 204996608);
    float* G    = (float*)(ws + 205520896);
    float* NQ   = (float*)(ws + 207618048);
    float* NK   = (float*)(ws + 207650816);
    bf16*  P    = (bf16*)(ws + 207683584);
    int*   flag = (int*)(ws + 208732160);
    float* misc = (float*)(ws + 208732224);

    bf16* V0 = (bf16*)d_out;               // V scratch in d_out (always bf16)
    bf16* V1 = (bf16*)d_out + PART_STRIDE;

    hipMemsetAsync(ws + 205520896, 0, 2162688, stream);   // zero G + NQ + NK

    detect_kernel<<<1, 256, 0, stream>>>((const bf16*)Wq0, flag);
    misc_kernel<<<1, 256, 0, stream>>>(temp0, temp1, bp0, bp1, flag, misc);

    wt_kernel<<<(512 * 1536 + 255) / 256, 256, 0, stream>>>(Wq0, wtq0, 512, 1536, flag);
    wt_kernel<<<(512 * 1536 + 255) / 256, 256, 0, stream>>>(Wq1, wtq1, 512, 1536, flag);
    wt_kernel<<<(512 * 512 + 255) / 256, 256, 0, stream>>>(Wp0, wtp0, 512, 512, flag);
    wt_kernel<<<(512 * 512 + 255) / 256, 256, 0, stream>>>(Wp1, wtp1, 512, 512, flag);

    cast_kernel<<<8192, 256, 0, stream>>>(x,   Xb0, flag);
    cast_kernel<<<8192, 256, 0, stream>>>(x_d, Xb1, flag);

    // QKV: parts 0/1 -> Q,K in ws; part 2 -> V scratch in d_out
    gemm_bt<<<dim3(128, 6), 512, 0, stream>>>(Xb0, wtq0, nullptr, Q0, V0, 0L, nullptr);
    gemm_bt<<<dim3(128, 6), 512, 0, stream>>>(Xb1, wtq1, nullptr, Q1, V1, 0L, nullptr);

    xca_gk<<<512, 256, 0, stream>>>(Q0, K0, Q1, K1, G, NQ, NK);
    xca_soft<<<128, 64, 0, stream>>>(G, NQ, NK, misc, P);
    xca_pv<<<512, 256, 0, stream>>>(V0, V1, P, xca);

    // proj GEMMs: out dtype per flag; 2nd half at element offset PART_STRIDE
    gemm_bt<<<dim3(128, 2), 512, 0, stream>>>(xca,               wtp0, misc + 16,  d_out, nullptr, 0L,          flag);
    gemm_bt<<<dim3(128, 2), 512, 0, stream>>>(xca + PART_STRIDE, wtp1, misc + 528, d_out, nullptr, PART_STRIDE, flag);
}

// Round 2
// 528.879 us; speedup vs baseline: 1.3840x; 1.1109x over previous
//
#include <hip/hip_runtime.h>
#include <hip/hip_bf16.h>
#include <math.h>
#include <stdint.h>

typedef __bf16 bf16;
typedef __bf16 bf16x8 __attribute__((ext_vector_type(8)));
typedef float  floatx4 __attribute__((ext_vector_type(4)));

#define HEADS 8
#define DH    64
#define NB    8
#define NTOK  4096
#define CDIM  512
#define MTOT  32768
#define PART_STRIDE 16777216L   // elements: 32768*512

// async global->LDS, 16B per lane; LDS dst = wave-uniform base + lane*16 (m97/m104)
__device__ __forceinline__ void gload16(const bf16* g, bf16* l) {
    __builtin_amdgcn_global_load_lds(
        (const __attribute__((address_space(1))) unsigned int*)g,
        (__attribute__((address_space(3))) unsigned int*)l,
        16, 0, 0);
}

__global__ void detect_kernel(const bf16* __restrict__ w, int* __restrict__ flag)
{
    __shared__ int cnt[256];
    int c = 0;
    for (int i = 0; i < 64; ++i) {
        float v = fabsf((float)w[threadIdx.x + i * 256]);
        if (v > 1e3f) c++;
    }
    cnt[threadIdx.x] = c;
    __syncthreads();
    if (threadIdx.x == 0) {
        int s = 0;
        for (int i = 0; i < 256; ++i) s += cnt[i];
        *flag = (s > 500) ? 1 : 0;   // 1 => inputs are fp32
    }
}

// misc floats: [0..7] temp0, [8..15] temp1, [16..527] bias0, [528..1039] bias1
__global__ void misc_kernel(const void* t0, const void* t1, const void* b0, const void* b1,
                            const int* __restrict__ flag, float* __restrict__ misc)
{
    bool f32 = (*flag != 0);
    int tid = threadIdx.x;
    #define RD(p, i) (f32 ? ((const float*)(p))[i] : (float)((const bf16*)(p))[i])
    if (tid < 8) { misc[tid] = RD(t0, tid); misc[8 + tid] = RD(t1, tid); }
    for (int i = tid; i < 512; i += 256) {
        misc[16 + i]  = RD(b0, i);
        misc[528 + i] = RD(b1, i);
    }
    #undef RD
}

__global__ void wt_kernel(const void* __restrict__ W, bf16* __restrict__ Wt, int K, int N,
                          const int* __restrict__ flag)
{
    int idx = blockIdx.x * 256 + threadIdx.x;
    if (idx >= K * N) return;
    bool f32 = (*flag != 0);
    int n = idx / K;
    int k = idx - n * K;
    float v = f32 ? ((const float*)W)[k * N + n] : (float)((const bf16*)W)[k * N + n];
    Wt[idx] = (bf16)v;
}

// X (fp32 or bf16 per flag) -> Y bf16; 8 elements/thread, 16,777,216 elements
__global__ void cast_kernel(const void* __restrict__ X, bf16* __restrict__ Y,
                            const int* __restrict__ flag)
{
    size_t i = ((size_t)blockIdx.x * 256 + threadIdx.x) * 8;
    if (*flag) {
        const float* xf = (const float*)X + i;
        float4 a = *(const float4*)xf;
        float4 b = *(const float4*)(xf + 4);
        bf16 t[8] = {(bf16)a.x, (bf16)a.y, (bf16)a.z, (bf16)a.w,
                     (bf16)b.x, (bf16)b.y, (bf16)b.z, (bf16)b.w};
        *(uint4*)(Y + i) = *(uint4*)t;
    } else {
        *(uint4*)(Y + i) = *(const uint4*)((const bf16*)X + i);
    }
}

// ---------------------------------------------------------------------------
// C = A[M][512] * Bt[N][512]^T (+bias), bf16 in, K=512 fixed.
// 256x256 tile, BK=64, 512 thr / 8 waves (2M x 4N), 8-phase pipelined schedule
// (m201 template) with counted vmcnt. See round-1 notes.
// ---------------------------------------------------------------------------
__global__ __launch_bounds__(512, 2) void gemm_bt(
    const bf16* __restrict__ A, const bf16* __restrict__ Bt,
    const float* __restrict__ bias, void* __restrict__ C, bf16* __restrict__ Cv,
    long c_base, const int* __restrict__ cflag)
{
    __shared__ bf16 lds[2][2][2][128 * 64];   // [buf][A=0/B=1][half][row*64 + swz-slot]

    const int tid  = threadIdx.x;
    const int lane = tid & 63;
    const int w    = tid >> 6;
    const int wmi  = w >> 2;        // 0..1 : wave M-half
    const int wni  = w & 3;         // 0..3 : wave N-quarter
    const int l15  = lane & 15;
    const int quad = lane >> 4;

    const int m0 = blockIdx.x * 256;
    const int n0 = blockIdx.y * 256;

    // staging: inst i in {0,1}: local row = w*16 + i*8 + (lane>>3), phys slot p = lane&7,
    // fetch logical 16B slot s = p ^ (row&7)  (row&7 invariant under +8)
    const int rl0 = w * 16 + (lane >> 3);
    const int swz = ((lane & 7) ^ (rl0 & 7)) * 8;      // element offset of fetched chunk
    const bf16* Abase = A  + (size_t)(m0 + rl0) * 512 + swz;
    const bf16* Bbase = Bt + (size_t)(n0 + rl0) * 512 + swz;
    const int ldst0 = w * 1024;                         // LDS element offset, inst0

    // compute side: logical slot s = ks*4+quad, phys slot = s ^ (row&7), row&7 == l15&7
    const int rxor  = l15 & 7;
    const int k0off = (quad ^ rxor) * 8;
    const int k1off = ((4 + quad) ^ rxor) * 8;
    const bf16* Ah0 = &lds[0][0][wmi][l15 * 64];
    const bf16* Ah1 = &lds[1][0][wmi][l15 * 64];
    const bf16* Bh0 = &lds[0][1][wni >> 1][((wni & 1) * 64 + l15) * 64];
    const bf16* Bh1 = &lds[1][1][wni >> 1][((wni & 1) * 64 + l15) * 64];

    bf16x8 aR[4][2], bR[4][2];
    floatx4 acc[8][4] = {};

#define STAGE_A(b, h, t) do { \
    const bf16* _g = Abase + (h) * 65536 + (t) * 64; \
    gload16(_g,        &lds[b][0][h][ldst0]); \
    gload16(_g + 4096, &lds[b][0][h][ldst0 + 512]); \
} while (0)
#define STAGE_B(b, h, t) do { \
    const bf16* _g = Bbase + (h) * 65536 + (t) * 64; \
    gload16(_g,        &lds[b][1][h][ldst0]); \
    gload16(_g + 4096, &lds[b][1][h][ldst0 + 512]); \
} while (0)
#define RD_A(b, qm) do { \
    _Pragma("unroll") for (int _i = 0; _i < 4; ++_i) { \
        aR[_i][0] = *(const bf16x8*)(Ah##b + ((qm) * 4 + _i) * 1024 + k0off); \
        aR[_i][1] = *(const bf16x8*)(Ah##b + ((qm) * 4 + _i) * 1024 + k1off); \
    } \
} while (0)
#define RD_B(b, qn) do { \
    _Pragma("unroll") for (int _j = 0; _j < 2; ++_j) { \
        bR[(qn) * 2 + _j][0] = *(const bf16x8*)(Bh##b + ((qn) * 2 + _j) * 1024 + k0off); \
        bR[(qn) * 2 + _j][1] = *(const bf16x8*)(Bh##b + ((qn) * 2 + _j) * 1024 + k1off); \
    } \
} while (0)
#define MM(qm, qn) do { \
    _Pragma("unroll") for (int _i = 0; _i < 4; ++_i) \
    _Pragma("unroll") for (int _j = 0; _j < 2; ++_j) { \
        acc[(qm)*4+_i][(qn)*2+_j] = __builtin_amdgcn_mfma_f32_16x16x32_bf16( \
            aR[_i][0], bR[(qn)*2+_j][0], acc[(qm)*4+_i][(qn)*2+_j], 0, 0, 0); \
        acc[(qm)*4+_i][(qn)*2+_j] = __builtin_amdgcn_mfma_f32_16x16x32_bf16( \
            aR[_i][1], bR[(qn)*2+_j][1], acc[(qm)*4+_i][(qn)*2+_j], 0, 0, 0); \
    } \
} while (0)
#define SYNC   asm volatile("s_barrier" ::: "memory")
#define VMW(n) asm volatile("s_waitcnt vmcnt(" #n ")" ::: "memory")
#define PRIO1  __builtin_amdgcn_s_setprio(1)
#define PRIO0  __builtin_amdgcn_s_setprio(0)

#define TILE(t, b, nb, W) do { \
    /* q0 (Mlo,Nlo) */ \
    RD_A(b, 0); RD_B(b, 0); \
    if ((t) + 1 < 8) STAGE_B(nb, 1, (t) + 1); \
    SYNC; PRIO1; MM(0, 0); PRIO0; SYNC; \
    /* q1 (Mlo,Nhi) */ \
    RD_B(b, 1); \
    if ((t) + 1 < 8) STAGE_A(nb, 1, (t) + 1); \
    SYNC; PRIO1; MM(0, 1); PRIO0; SYNC; \
    /* q2 (Mhi,Nhi) */ \
    RD_A(b, 1); \
    if ((t) + 2 < 8) STAGE_B(b, 0, (t) + 2); \
    SYNC; PRIO1; MM(1, 1); PRIO0; SYNC; \
    /* q3 (Mhi,Nlo) */ \
    if ((t) + 2 < 8) STAGE_A(b, 0, (t) + 2); \
    SYNC; PRIO1; MM(1, 0); PRIO0; \
    VMW(W); SYNC; \
} while (0)

    // prologue: tile0 (4 halves) + B0/A0 of tile1; then tile0 done with 4 in flight
    STAGE_A(0, 0, 0); STAGE_A(0, 1, 0); STAGE_B(0, 0, 0); STAGE_B(0, 1, 0);
    STAGE_B(1, 0, 1); STAGE_A(1, 0, 1);
    VMW(4);
    SYNC;

    TILE(0, 0, 1, 4);
    TILE(1, 1, 0, 4);
    TILE(2, 0, 1, 4);
    TILE(3, 1, 0, 4);
    TILE(4, 0, 1, 4);
    TILE(5, 1, 0, 4);
    TILE(6, 0, 1, 0);   // tail: prefetches of t+2 skipped -> drain before tile 7
    TILE(7, 1, 0, 0);

#undef TILE
#undef STAGE_A
#undef STAGE_B
#undef RD_A
#undef RD_B
#undef MM
#undef SYNC
#undef VMW
#undef PRIO1
#undef PRIO0

    // epilogue: D layout col=lane&15, row=quad*4+reg (m89/m91).
    // n-range of a block (256 wide, n0 multiple of 256) sits in a single part.
    const bool cf32 = cflag && (*cflag != 0);
    const int  part = n0 >> 9;
    const long rowB = (long)m0 + wmi * 128 + quad * 4;
    const int  colB = (n0 & 511) + wni * 64 + l15;

    float bv[4];
    #pragma unroll
    for (int fj = 0; fj < 4; ++fj)
        bv[fj] = bias ? bias[n0 + wni * 64 + fj * 16 + l15] : 0.0f;

    if (part == 2) {
        #pragma unroll
        for (int fi = 0; fi < 8; ++fi)
            #pragma unroll
            for (int rr = 0; rr < 4; ++rr) {
                bf16* op = Cv + (rowB + fi * 16 + rr) * CDIM + colB;
                #pragma unroll
                for (int fj = 0; fj < 4; ++fj)
                    op[fj * 16] = (bf16)acc[fi][fj][rr];
            }
    } else if (cf32) {
        float* Cp = (float*)C + c_base + (long)part * PART_STRIDE;
        #pragma unroll
        for (int fi = 0; fi < 8; ++fi)
            #pragma unroll
            for (int rr = 0; rr < 4; ++rr) {
                float* op = Cp + (rowB + fi * 16 + rr) * CDIM + colB;
                #pragma unroll
                for (int fj = 0; fj < 4; ++fj)
                    op[fj * 16] = acc[fi][fj][rr] + bv[fj];
            }
    } else {
        bf16* Cp = (bf16*)C + c_base + (long)part * PART_STRIDE;
        #pragma unroll
        for (int fi = 0; fi < 8; ++fi)
            #pragma unroll
            for (int rr = 0; rr < 4; ++rr) {
                bf16* op = Cp + (rowB + fi * 16 + rr) * CDIM + colB;
                #pragma unroll
                for (int fj = 0; fj < 4; ++fj)
                    op[fj * 16] = (bf16)(acc[fi][fj][rr] + bv[fj]);
            }
    }
}

// ---------------------------------------------------------------------------
// xca_gk: G[sbh][d][e] = sum_n Q[n][d] K[n][e]  via MFMA (gram over token axis),
// plus NQ/NK = diagonals of Q^T Q / K^T K (2 extra MFMA per wave per k-step).
// 64-token tiles transpose-staged in LDS [64 d][72] (144B rows, b128-aligned).
// Token-pair XOR swizzle u' = u ^ ((d>>3)<<2): writes 2-way (free), reads at
// b128 floor. 4 waves = 2x2 over the 64x64 G output; 1-deep reg prefetch.
// ---------------------------------------------------------------------------
__global__ __launch_bounds__(256) void xca_gk(
    const bf16* __restrict__ Q0, const bf16* __restrict__ K0,
    const bf16* __restrict__ Q1, const bf16* __restrict__ K1,
    float* __restrict__ G, float* __restrict__ NQ, float* __restrict__ NK)
{
    __shared__ bf16 Tq[64 * 72];
    __shared__ bf16 Tk[64 * 72];

    int bid = blockIdx.x;
    int nq4 = bid & 3;
    int h   = (bid >> 2) & 7;
    int b   = (bid >> 5) & 7;
    int s   = bid >> 8;
    int sbh = s * 64 + b * 8 + h;

    const bf16* qsrc = s ? Q1 : Q0;
    const bf16* ksrc = s ? K0 : K1;

    int tid  = threadIdx.x;
    int lane = tid & 63;
    int wv   = tid >> 6;
    int wr   = wv >> 1;              // G row-block (d of Q)
    int wc   = wv & 1;               // G col-block (e of K)
    int l15  = lane & 15;
    int quad = lane >> 4;
    bool isQ = (wv == 0 || wv == 3); // norm duty: waves 0,3 -> NQ; 1,2 -> NK

    // staging map: token-pair u = tid>>3 (tokens 2u,2u+1), d-chunk d0 = (tid&7)*8
    int m_thr = tid & 7;
    int d0    = m_thr * 8;
    int u     = tid >> 3;
    int u_w   = u ^ (m_thr << 2);            // bank swizzle (write side)
    int wbase = d0 * 72 + 2 * u_w;           // element offset for j=0

    // frag read offsets: row r, logical token-pair block ulog, swz by (r>>3)<<2
    int aoff[2][2], boff[2][2];
    #pragma unroll
    for (int i = 0; i < 2; ++i) {
        int ra = wr * 32 + i * 16 + l15;
        int rb = wc * 32 + i * 16 + l15;
        #pragma unroll
        for (int ss = 0; ss < 2; ++ss) {
            int ulog = ss * 16 + quad * 4;
            aoff[i][ss] = ra * 72 + 2 * (ulog ^ ((ra >> 3) << 2));
            boff[i][ss] = rb * 72 + 2 * (ulog ^ ((rb >> 3) << 2));
        }
    }

    long gbase = (long)(b * NTOK + nq4 * 1024) * CDIM + h * DH + d0;
    const bf16* qg = qsrc + gbase;
    const bf16* kg = ksrc + gbase;

    floatx4 accG[2][2] = {};
    floatx4 accN[2] = {};

    uint4 qA, qB, kA, kB;
    {
        size_t off = (size_t)(2 * u) * CDIM;
        qA = *(const uint4*)(qg + off);
        qB = *(const uint4*)(qg + off + CDIM);
        kA = *(const uint4*)(kg + off);
        kB = *(const uint4*)(kg + off + CDIM);
    }

    for (int t = 0; t < 16; ++t) {
        __syncthreads();   // prev tile's reads complete
        {
            const unsigned short* pa = (const unsigned short*)&qA;
            const unsigned short* pb = (const unsigned short*)&qB;
            const unsigned short* pc = (const unsigned short*)&kA;
            const unsigned short* pd = (const unsigned short*)&kB;
            #pragma unroll
            for (int j = 0; j < 8; ++j) {
                *(uint32_t*)((char*)Tq + (size_t)(wbase + j * 72) * 2) =
                    (uint32_t)pa[j] | ((uint32_t)pb[j] << 16);
                *(uint32_t*)((char*)Tk + (size_t)(wbase + j * 72) * 2) =
                    (uint32_t)pc[j] | ((uint32_t)pd[j] << 16);
            }
        }
        __syncthreads();
        if (t + 1 < 16) {   // prefetch next tile into regs (hides HBM latency)
            size_t off = (size_t)((t + 1) * 64 + 2 * u) * CDIM;
            qA = *(const uint4*)(qg + off);
            qB = *(const uint4*)(qg + off + CDIM);
            kA = *(const uint4*)(kg + off);
            kB = *(const uint4*)(kg + off + CDIM);
        }
        #pragma unroll
        for (int ss = 0; ss < 2; ++ss) {
            bf16x8 a0 = *(const bf16x8*)&Tq[aoff[0][ss]];
            bf16x8 a1 = *(const bf16x8*)&Tq[aoff[1][ss]];
            bf16x8 b0 = *(const bf16x8*)&Tk[boff[0][ss]];
            bf16x8 b1 = *(const bf16x8*)&Tk[boff[1][ss]];
            accG[0][0] = __builtin_amdgcn_mfma_f32_16x16x32_bf16(a0, b0, accG[0][0], 0, 0, 0);
            accG[0][1] = __builtin_amdgcn_mfma_f32_16x16x32_bf16(a0, b1, accG[0][1], 0, 0, 0);
            accG[1][0] = __builtin_amdgcn_mfma_f32_16x16x32_bf16(a1, b0, accG[1][0], 0, 0, 0);
            accG[1][1] = __builtin_amdgcn_mfma_f32_16x16x32_bf16(a1, b1, accG[1][1], 0, 0, 0);
            if (isQ) {
                accN[0] = __builtin_amdgcn_mfma_f32_16x16x32_bf16(a0, a0, accN[0], 0, 0, 0);
                accN[1] = __builtin_amdgcn_mfma_f32_16x16x32_bf16(a1, a1, accN[1], 0, 0, 0);
            } else {
                accN[0] = __builtin_amdgcn_mfma_f32_16x16x32_bf16(b0, b0, accN[0], 0, 0, 0);
                accN[1] = __builtin_amdgcn_mfma_f32_16x16x32_bf16(b1, b1, accN[1], 0, 0, 0);
            }
        }
    }

    // G[d][e]: rows wr*32+i*16+quad*4+rr, cols wc*32+j*16+l15 (m89 D-layout)
    float* Gp = G + (size_t)sbh * 4096;
    #pragma unroll
    for (int i = 0; i < 2; ++i)
        #pragma unroll
        for (int j = 0; j < 2; ++j)
            #pragma unroll
            for (int rr = 0; rr < 4; ++rr)
                atomicAdd(&Gp[(wr * 32 + i * 16 + quad * 4 + rr) * 64 + wc * 32 + j * 16 + l15],
                          accG[i][j][rr]);

    // norms = gram diagonals: lane holds (row=quad*4+rr, col=l15); diag iff l15>>2==quad
    float* Np  = isQ ? NQ : NK;
    int nbase  = (isQ ? wr : wc) * 32;
    if ((l15 >> 2) == quad) {
        atomicAdd(&Np[(size_t)sbh * 64 + nbase + l15],      accN[0][l15 & 3]);
        atomicAdd(&Np[(size_t)sbh * 64 + nbase + 16 + l15], accN[1][l15 & 3]);
    }
}

__global__ void xca_soft(const float* __restrict__ G,
                         const float* __restrict__ NQ, const float* __restrict__ NK,
                         const float* __restrict__ misc, bf16* __restrict__ P)
{
    int sbh = blockIdx.x;
    int s = sbh >> 6;
    int h = sbh & 7;
    int d = threadIdx.x;

    __shared__ float rk[64];
    rk[d] = 1.0f / fmaxf(sqrtf(NK[sbh * 64 + d]), 1e-12f);
    __syncthreads();

    float rq = 1.0f / fmaxf(sqrtf(NQ[sbh * 64 + d]), 1e-12f);
    float t  = misc[s * 8 + h];
    const float* Gr = G + (sbh * 64 + d) * 64;

    float a[64];
    float mx = -1e30f;
    #pragma unroll
    for (int e = 0; e < 64; ++e) {
        a[e] = Gr[e] * rq * rk[e] * t;
        mx = fmaxf(mx, a[e]);
    }
    float sum = 0.f;
    #pragma unroll
    for (int e = 0; e < 64; ++e) { a[e] = expf(a[e] - mx); sum += a[e]; }
    float inv = 1.0f / sum;
    bf16* Pr = P + (sbh * 64 + d) * 64;
    #pragma unroll
    for (int e = 0; e < 64; ++e) Pr[e] = (bf16)(a[e] * inv);
}

__global__ __launch_bounds__(256) void xca_pv(
    const bf16* __restrict__ V0, const bf16* __restrict__ V1,
    const bf16* __restrict__ P, bf16* __restrict__ xca)
{
    int bid = blockIdx.x;
    int nq4 = bid & 3;
    int h   = (bid >> 2) & 7;
    int b   = (bid >> 5) & 7;
    int s   = bid >> 8;
    int sbh = s * 64 + b * 8 + h;

    const bf16* vsrc = s ? V0 : V1;

    int tid = threadIdx.x;
    int lane = tid & 63;
    int wave = tid >> 6;
    int l15 = lane & 15;
    int quad = lane >> 4;

    const bf16* Pb = P + sbh * 4096;
    bf16x8 pf[4][2];
    #pragma unroll
    for (int i = 0; i < 4; ++i)
        #pragma unroll
        for (int h2 = 0; h2 < 2; ++h2)
            pf[i][h2] = *(const bf16x8*)&Pb[(i * 16 + l15) * 64 + h2 * 32 + quad * 8];

    int n_start = nq4 * 1024 + wave * 256;
    for (int nt = 0; nt < 16; ++nt) {
        int nb = n_start + nt * 16;
        const bf16* vp = vsrc + (long)(b * NTOK + nb + l15) * CDIM + h * DH + quad * 8;
        bf16x8 v0 = *(const bf16x8*)vp;
        bf16x8 v1 = *(const bf16x8*)(vp + 32);
        floatx4 acc[4] = {};
        #pragma unroll
        for (int i = 0; i < 4; ++i) {
            acc[i] = __builtin_amdgcn_mfma_f32_16x16x32_bf16(v0, pf[i][0], acc[i], 0, 0, 0);
            acc[i] = __builtin_amdgcn_mfma_f32_16x16x32_bf16(v1, pf[i][1], acc[i], 0, 0, 0);
        }
        bf16* op = xca + (long)((s * NB + b) * NTOK + nb + quad * 4) * CDIM + h * DH + l15;
        #pragma unroll
        for (int i = 0; i < 4; ++i)
            #pragma unroll
            for (int r = 0; r < 4; ++r)
                op[(long)r * CDIM + i * 16] = (bf16)acc[i][r];
    }
}

// ws layout (bytes), total ~208.7 MB:
//   0           Q0 (33,554,432)
//   33,554,432  K0 (33,554,432)
//   67,108,864  Q1 (33,554,432)
//   100,663,296 K1 (33,554,432)
//   134,217,728 Xb0 (33,554,432)  -- bf16 cast of x;  xca overlay after QKV gemms
//   167,772,160 Xb1 (33,554,432)  -- bf16 cast of x_d
//   201,326,592 wtq0 (1,572,864)
//   202,899,456 wtq1 (1,572,864)
//   204,472,320 wtp0 (524,288)
//   204,996,608 wtp1 (524,288)
//   205,520,896 G    (2,097,152 fp32)
//   207,618,048 NQ   (32,768)
//   207,650,816 NK   (32,768)
//   207,683,584 P    (1,048,576)
//   208,732,160 flag (64)
//   208,732,224 misc (4,160)
// V0/V1 in d_out (dead scratch until the final proj overwrites it).
extern "C" void kernel_launch(void* const* d_in, const int* in_sizes, int n_in,
                              void* d_out, int out_size, void* d_ws, size_t ws_size,
                              hipStream_t stream)
{
    const void* x     = d_in[0];
    const void* x_d   = d_in[1];
    const void* Wq0   = d_in[2];
    const void* Wq1   = d_in[3];
    const void* temp0 = d_in[4];
    const void* temp1 = d_in[5];
    const void* Wp0   = d_in[6];
    const void* bp0   = d_in[7];
    const void* Wp1   = d_in[8];
    const void* bp1   = d_in[9];

    char* ws = (char*)d_ws;
    bf16*  Q0   = (bf16*)(ws);
    bf16*  K0   = (bf16*)(ws + 33554432);
    bf16*  Q1   = (bf16*)(ws + 67108864);
    bf16*  K1   = (bf16*)(ws + 100663296);
    bf16*  Xb0  = (bf16*)(ws + 134217728);
    bf16*  Xb1  = (bf16*)(ws + 167772160);
    bf16*  xca  = (bf16*)(ws + 134217728);  // overlay on Xb0+Xb1 (dead after QKV gemms)
    bf16*  wtq0 = (bf16*)(ws + 201326592);
    bf16*  wtq1 = (bf16*)(ws + 202899456);
    bf16*  wtp0 = (bf16*)(ws + 204472320);
    bf16*  wtp1 = (bf16*)(ws + 204996608);
    float* G    = (float*)(ws + 205520896);
    float* NQ   = (float*)(ws + 207618048);
    float* NK   = (float*)(ws + 207650816);
    bf16*  P    = (bf16*)(ws + 207683584);
    int*   flag = (int*)(ws + 208732160);
    float* misc = (float*)(ws + 208732224);

    bf16* V0 = (bf16*)d_out;               // V scratch in d_out (always bf16)
    bf16* V1 = (bf16*)d_out + PART_STRIDE;

    hipMemsetAsync(ws + 205520896, 0, 2162688, stream);   // zero G + NQ + NK

    detect_kernel<<<1, 256, 0, stream>>>((const bf16*)Wq0, flag);
    misc_kernel<<<1, 256, 0, stream>>>(temp0, temp1, bp0, bp1, flag, misc);

    wt_kernel<<<(512 * 1536 + 255) / 256, 256, 0, stream>>>(Wq0, wtq0, 512, 1536, flag);
    wt_kernel<<<(512 * 1536 + 255) / 256, 256, 0, stream>>>(Wq1, wtq1, 512, 1536, flag);
    wt_kernel<<<(512 * 512 + 255) / 256, 256, 0, stream>>>(Wp0, wtp0, 512, 512, flag);
    wt_kernel<<<(512 * 512 + 255) / 256, 256, 0, stream>>>(Wp1, wtp1, 512, 512, flag);

    cast_kernel<<<8192, 256, 0, stream>>>(x,   Xb0, flag);
    cast_kernel<<<8192, 256, 0, stream>>>(x_d, Xb1, flag);

    // QKV: parts 0/1 -> Q,K in ws; part 2 -> V scratch in d_out
    gemm_bt<<<dim3(128, 6), 512, 0, stream>>>(Xb0, wtq0, nullptr, Q0, V0, 0L, nullptr);
    gemm_bt<<<dim3(128, 6), 512, 0, stream>>>(Xb1, wtq1, nullptr, Q1, V1, 0L, nullptr);

    xca_gk<<<512, 256, 0, stream>>>(Q0, K0, Q1, K1, G, NQ, NK);
    xca_soft<<<128, 64, 0, stream>>>(G, NQ, NK, misc, P);
    xca_pv<<<512, 256, 0, stream>>>(V0, V1, P, xca);

    // proj GEMMs: out dtype per flag; 2nd half at element offset PART_STRIDE
    gemm_bt<<<dim3(128, 2), 512, 0, stream>>>(xca,               wtp0, misc + 16,  d_out, nullptr, 0L,          flag);
    gemm_bt<<<dim3(128, 2), 512, 0, stream>>>(xca + PART_STRIDE, wtp1, misc + 528, d_out, nullptr, PART_STRIDE, flag);
}